// Round 2
// baseline (2632.887 us; speedup 1.0000x reference)
//
#include <hip/hip_runtime.h>
#include <stdint.h>

#define RES 8192
#define TSTEPS 512
#define CAP 1024                         // padded slots per row (mean nnz 819, 7.5 sigma headroom)
#define NB 256
#define NT 512
#define ROWS_PER_BLOCK (RES / NB)        // 32
#define LANES_PER_ROW (NT / ROWS_PER_BLOCK) // 16
#define VEC_ITERS (CAP / LANES_PER_ROW / 4) // 16

// workspace layout
#define WS_PACKED_OFF   0
#define WS_HHIST_OFF    (33554432u)                  // 8192*1024*4
#define WS_BAR_OFF      (33554432u + 16809984u)      // + 513*8192*4  = 50364416

__global__ __launch_bounds__(256) void esn_compress(const float* __restrict__ W,
                                                    uint32_t* __restrict__ packed) {
    const int wave = threadIdx.x >> 6;
    const int lane = threadIdx.x & 63;
    const int row  = blockIdx.x * 4 + wave;
    const float* wrow = W + (size_t)row * RES;
    uint32_t* prow = packed + (size_t)row * CAP;
    unsigned nnz = 0;
    for (int chunk = 0; chunk < RES / 64; ++chunk) {
        const int c = chunk * 64 + lane;
        const float v = wrow[c];
        const bool nz = (v != 0.0f);
        const unsigned long long m = __ballot(nz);
        if (nz) {
            unsigned pos = nnz + (unsigned)__popcll(m & ((1ull << lane) - 1ull));
            if (pos < CAP) {
                uint32_t b = __float_as_uint(v);
                b += 0x1000u;                       // round-to-nearest at 19-bit cut
                prow[pos] = ((uint32_t)c << 19) | (b >> 13);
            }
        }
        nnz += (unsigned)__popcll(m);
    }
    if (nnz > CAP) nnz = CAP;
    for (unsigned s = nnz + (unsigned)lane; s < CAP; s += 64) prow[s] = 0u;  // pad: idx 0, val +0.0
}

__device__ __forceinline__ void waitcnt0() { asm volatile("s_waitcnt vmcnt(0)" ::: "memory"); }

__global__ __launch_bounds__(NT) void esn_loop(const float* __restrict__ x,
                                               const float* __restrict__ Win,
                                               const float* __restrict__ Wout_w,
                                               const float* __restrict__ Wout_b,
                                               const uint32_t* __restrict__ packed,
                                               float* __restrict__ h_hist,
                                               unsigned* __restrict__ bar,
                                               float* __restrict__ out) {
    __shared__ float lds_h[RES];
    __shared__ float lds_red[NT / 64][3];

    const int tid = threadIdx.x;
    const int bid = blockIdx.x;
    const int li  = tid & (LANES_PER_ROW - 1);
    const int row = bid * ROWS_PER_BLOCK + (tid >> 4);
    const bool leader = (li == 0);

    float win0 = 0.f, win1 = 0.f, win2 = 0.f;
    if (leader) {
        win0 = Win[row * 3 + 0];
        win1 = Win[row * 3 + 1];
        win2 = Win[row * 3 + 2];
    }

    const uint4* prow = ((const uint4*)packed) + (size_t)row * (CAP / 4);

    for (int t = 0; t < TSTEPS; ++t) {
        // ---- stage h_t into LDS ----
        float4* d = (float4*)lds_h;
        if (t == 0) {
            const float4 z4 = make_float4(0.f, 0.f, 0.f, 0.f);
            for (int i = tid; i < RES / 4; i += NT) d[i] = z4;
        } else {
            const float4* s = (const float4*)(h_hist + (size_t)t * RES);
            for (int i = tid; i < RES / 4; i += NT) d[i] = s[i];
        }
        __syncthreads();

        // ---- sparse dot: this lane's slots of its row ----
        float acc = 0.f;
#pragma unroll
        for (int i = 0; i < VEC_ITERS; ++i) {
            const uint4 p = prow[i * LANES_PER_ROW + li];
            acc += __uint_as_float(p.x << 13) * lds_h[p.x >> 19];
            acc += __uint_as_float(p.y << 13) * lds_h[p.y >> 19];
            acc += __uint_as_float(p.z << 13) * lds_h[p.z >> 19];
            acc += __uint_as_float(p.w << 13) * lds_h[p.w >> 19];
        }
#pragma unroll
        for (int off = LANES_PER_ROW / 2; off >= 1; off >>= 1)
            acc += __shfl_xor(acc, off, LANES_PER_ROW);

        if (leader) {
            const float z = acc + win0 * x[t * 3 + 0] + win1 * x[t * 3 + 1] + win2 * x[t * 3 + 2];
            const float h = tanhf(z);
            // write-through (device-coherent) store so other XCDs see it next step
            __hip_atomic_store(&h_hist[(size_t)(t + 1) * RES + row], h,
                               __ATOMIC_RELAXED, __HIP_MEMORY_SCOPE_AGENT);
        }

        // ---- grid barrier (hierarchical, monotonic counters) ----
        __syncthreads();   // compiler drains vmcnt before s_barrier -> h stores complete
        if (tid == 0) {
            waitcnt0();
            const int g = bid & 7;
            const unsigned gprev = __hip_atomic_fetch_add(&bar[g * 32], 1u,
                                      __ATOMIC_RELAXED, __HIP_MEMORY_SCOPE_AGENT);
            if (gprev == (unsigned)((t + 1) * (NB / 8)) - 1u) {
                const unsigned mprev = __hip_atomic_fetch_add(&bar[8 * 32], 1u,
                                          __ATOMIC_RELAXED, __HIP_MEMORY_SCOPE_AGENT);
                if (mprev == (unsigned)((t + 1) * 8) - 1u) {
                    __hip_atomic_store(&bar[9 * 32], (unsigned)(t + 1),
                                       __ATOMIC_RELAXED, __HIP_MEMORY_SCOPE_AGENT);
                }
            }
            while (__hip_atomic_load(&bar[9 * 32], __ATOMIC_RELAXED,
                                     __HIP_MEMORY_SCOPE_AGENT) < (unsigned)(t + 1)) {
                __builtin_amdgcn_s_sleep(2);
            }
            waitcnt0();
        }
        __syncthreads();
    }

    // ---- epilogue: y_t = Wout_w @ h_{t+1} + b, two t per block, deterministic order ----
    const float b0 = Wout_b[0], b1 = Wout_b[1], b2 = Wout_b[2];
    for (int pass = 0; pass < TSTEPS / NB; ++pass) {
        const int tout = bid * (TSTEPS / NB) + pass;
        __syncthreads();
        {
            const float4* s = (const float4*)(h_hist + (size_t)(tout + 1) * RES);
            float4* d = (float4*)lds_h;
            for (int i = tid; i < RES / 4; i += NT) d[i] = s[i];
        }
        __syncthreads();
        float s0 = 0.f, s1 = 0.f, s2 = 0.f;
        for (int i = tid; i < RES; i += NT) {
            const float hv = lds_h[i];
            s0 += Wout_w[i] * hv;
            s1 += Wout_w[RES + i] * hv;
            s2 += Wout_w[2 * RES + i] * hv;
        }
#pragma unroll
        for (int off = 32; off >= 1; off >>= 1) {
            s0 += __shfl_xor(s0, off, 64);
            s1 += __shfl_xor(s1, off, 64);
            s2 += __shfl_xor(s2, off, 64);
        }
        const int wv = tid >> 6;
        if ((tid & 63) == 0) { lds_red[wv][0] = s0; lds_red[wv][1] = s1; lds_red[wv][2] = s2; }
        __syncthreads();
        if (tid < 3) {
            float sum = 0.f;
            for (int w = 0; w < NT / 64; ++w) sum += lds_red[w][tid];
            out[tout * 3 + tid] = sum + (tid == 0 ? b0 : (tid == 1 ? b1 : b2));
        }
    }
}

extern "C" void kernel_launch(void* const* d_in, const int* in_sizes, int n_in,
                              void* d_out, int out_size, void* d_ws, size_t ws_size,
                              hipStream_t stream) {
    const float* x      = (const float*)d_in[0];
    const float* Win    = (const float*)d_in[1];
    const float* W      = (const float*)d_in[2];
    const float* Wout_w = (const float*)d_in[3];
    const float* Wout_b = (const float*)d_in[4];

    uint8_t* ws = (uint8_t*)d_ws;
    uint32_t* packed = (uint32_t*)(ws + WS_PACKED_OFF);
    float*    h_hist = (float*)(ws + WS_HHIST_OFF);
    unsigned* bar    = (unsigned*)(ws + WS_BAR_OFF);
    float*    out    = (float*)d_out;

    (void)hipMemsetAsync(bar, 0, 4096, stream);
    esn_compress<<<dim3(RES / 4), dim3(256), 0, stream>>>(W, packed);

    void* args[] = { (void*)&x, (void*)&Win, (void*)&Wout_w, (void*)&Wout_b,
                     (void*)&packed, (void*)&h_hist, (void*)&bar, (void*)&out };
    (void)hipLaunchCooperativeKernel((void*)esn_loop, dim3(NB), dim3(NT), args, 0u, stream);
}